// Round 3
// baseline (732.804 us; speedup 1.0000x reference)
//
#include <hip/hip_runtime.h>

namespace {

typedef __fp16 h2 __attribute__((ext_vector_type(2)));
typedef float f4 __attribute__((ext_vector_type(4)));

constexpr int H  = 16;
constexpr int NS = 256;   // H*H joint states
constexpr int T  = 512;
constexpr int D  = 64;
constexpr float SH  = 92.0f;  // per-step log2-domain shift (mean emission ~ -92)
constexpr float LN2 = 0.69314718055994530942f;

__device__ __forceinline__ h2 pk(float a, float b) {
  return __builtin_amdgcn_cvt_pkrtz(a, b);
}

__device__ __forceinline__ float dot2acc(h2 a, h2 b, float c) {
#if __has_builtin(__builtin_amdgcn_fdot2)
  return __builtin_amdgcn_fdot2(a, b, c, false);
#else
  return c + (float)a.x * (float)b.x + (float)a.y * (float)b.y;
#endif
}

// Emission log2-lik: einit + sum_d y[d]*dif[d], 4 independent accumulator chains.
__device__ __forceinline__ float emit64(const f4* __restrict__ y,
                                        const h2* __restrict__ dif2, float einit) {
  float e0 = einit, e1 = 0.f, e2 = 0.f, e3 = 0.f;
#pragma unroll
  for (int i = 0; i < 16; i += 4) {
    f4 v0 = y[i], v1 = y[i + 1], v2 = y[i + 2], v3 = y[i + 3];
    e0 = dot2acc(dif2[2 * i + 0], pk(v0.x, v0.y), e0);
    e0 = dot2acc(dif2[2 * i + 1], pk(v0.z, v0.w), e0);
    e1 = dot2acc(dif2[2 * i + 2], pk(v1.x, v1.y), e1);
    e1 = dot2acc(dif2[2 * i + 3], pk(v1.z, v1.w), e1);
    e2 = dot2acc(dif2[2 * i + 4], pk(v2.x, v2.y), e2);
    e2 = dot2acc(dif2[2 * i + 5], pk(v2.z, v2.w), e2);
    e3 = dot2acc(dif2[2 * i + 6], pk(v3.x, v3.y), e3);
    e3 = dot2acc(dif2[2 * i + 7], pk(v3.z, v3.w), e3);
  }
  return (e0 + e1) + (e2 + e3);
}

// Block-wide sum of v across 256 threads (two barriers, uniform control flow).
__device__ __forceinline__ float block_sum(float v, float* red, int s) {
#pragma unroll
  for (int o = 32; o >= 1; o >>= 1) v += __shfl_xor(v, o, 64);
  __syncthreads();                 // WAR on red from previous use
  if ((s & 63) == 0) red[s >> 6] = v;
  __syncthreads();
  return (red[0] + red[1]) + (red[2] + red[3]);
}

__global__ __launch_bounds__(256, 4) void fhmm_fwd(
    const float* __restrict__ seq,     // [B, T, D]
    const int*   __restrict__ lengths, // [B]
    const float* __restrict__ pw,      // [H, H]
    const float* __restrict__ px,      // [H, H]
    const float* __restrict__ py,      // [H, H, D]
    float*       __restrict__ out)     // [B]
{
  const int b  = blockIdx.x;
  const int s  = threadIdx.x;   // joint state = w*16 + x
  const int wq = s >> 4;
  const int xq = s & 15;

  __shared__ float a_lds[2][NS];
  __shared__ float red[4];

  // Per-thread emission params, log2 domain, f16-packed pairs (32 VGPRs).
  h2 dif2[32];
  float ebase;  // base2 + SH
  {
    float acc0 = 0.0f;
    const float* p = py + s * D;
#pragma unroll
    for (int i = 0; i < 32; ++i) {
      float v0 = p[2 * i], v1 = p[2 * i + 1];
      float l0 = __log2f(1.0f - v0), l1 = __log2f(1.0f - v1);
      acc0 += l0 + l1;
      dif2[i] = pk(__log2f(v0) - l0, __log2f(v1) - l1);
    }
    ebase = acc0 + SH;
  }

  // Transition columns (32 VGPRs): pwc[k]=pw[k][wq], pxc[k]=px[k][xq]
  float pwc[H], pxc[H];
#pragma unroll
  for (int k = 0; k < H; ++k) {
    pwc[k] = pw[k * H + wq];
    pxc[k] = px[k * H + xq];
  }

  const int len = lengths[b];
  const f4* y16 = (const f4*)(seq + (size_t)b * (T * D));

  // ---- t = 0
  float al  = pw[wq] * px[xq] * exp2f(emit64(y16, dif2, ebase));
  float acc = 0.0f;

  // ---- t = 1 .. len-1 ; one barrier per step (double-buffered alpha exchange)
  for (int t = 1; t < len; ++t) {
    float* buf = a_lds[t & 1];
    buf[s] = al;
    float em = emit64(y16 + t * 16, dif2, ebase);  // overlaps with barrier wait
    __syncthreads();

    // contract previous w: aw[w',x] = sum_w alpha[w,x] * pw[w][w']
    float aw0 = 0.f, aw1 = 0.f;
#pragma unroll
    for (int k = 0; k < 16; k += 2) {
      aw0 = fmaf(pwc[k],     buf[k * H + xq],       aw0);
      aw1 = fmaf(pwc[k + 1], buf[(k + 1) * H + xq], aw1);
    }
    const unsigned awu = __float_as_uint(aw0 + aw1);

    // contract previous x in-wave: the 16 aw values for fixed w' live in this
    // lane's own 16-lane group -> ds_swizzle broadcast, no LDS, no barrier.
    float an0 = 0.f, an1 = 0.f;
#define C2(K0, K1)                                                                        \
    an0 = fmaf(pxc[K0], __uint_as_float(__builtin_amdgcn_ds_swizzle(awu, ((K0) << 5) | 0x10)), an0); \
    an1 = fmaf(pxc[K1], __uint_as_float(__builtin_amdgcn_ds_swizzle(awu, ((K1) << 5) | 0x10)), an1);
    C2(0, 1) C2(2, 3) C2(4, 5) C2(6, 7)
    C2(8, 9) C2(10, 11) C2(12, 13) C2(14, 15)
#undef C2

    al = (an0 + an1) * exp2f(em);

    if ((t & 1) == 0) {  // renormalize every 2 steps (keeps fp32 in range)
      float S = block_sum(al, red, s);
      al *= __builtin_amdgcn_rcpf(S);
      acc += __log2f(S);
    }
  }

  float S = block_sum(al, red, s);
  acc += __log2f(S);
  if (s == 0) out[b] = (acc - SH * (float)len) * LN2;
}

} // namespace

extern "C" void kernel_launch(void* const* d_in, const int* in_sizes, int n_in,
                              void* d_out, int out_size, void* d_ws, size_t ws_size,
                              hipStream_t stream) {
  const float* seq     = (const float*)d_in[0];
  const int*   lengths = (const int*)d_in[1];
  const float* pw      = (const float*)d_in[2];
  const float* px      = (const float*)d_in[3];
  const float* py      = (const float*)d_in[4];
  float*       out     = (float*)d_out;

  hipLaunchKernelGGL(fhmm_fwd, dim3(1024), dim3(256), 0, stream,
                     seq, lengths, pw, px, py, out);
}

// Round 7
// 231.342 us; speedup vs baseline: 3.1676x; 3.1676x over previous
//
#include <hip/hip_runtime.h>

namespace {

typedef short    v4s __attribute__((ext_vector_type(4)));
typedef float    v4f __attribute__((ext_vector_type(4)));
typedef float    f4  __attribute__((ext_vector_type(4)));
typedef unsigned u2  __attribute__((ext_vector_type(2)));

constexpr int Tt = 512;
constexpr int Dd = 64;
constexpr float LN2 = 0.69314718055994530942f;

// RNE bf16 pack of two finite non-NaN floats -> u32 {lo16=bf16(a), hi16=bf16(b)}
// Pure bit ops (sign-magnitude correct for negatives). No asm.
__device__ __forceinline__ unsigned pk_bf16(float a, float b) {
  unsigned ua = __float_as_uint(a), ub = __float_as_uint(b);
  ua += 0x7fffu + ((ua >> 16) & 1u);
  ub += 0x7fffu + ((ub >> 16) & 1u);
  return (ua >> 16) | (ub & 0xffff0000u);
}
__device__ __forceinline__ v4s mk4(unsigned lo, unsigned hi) {
  union { unsigned u[2]; v4s s; } z;
  z.u[0] = lo; z.u[1] = hi; return z.s;
}
__device__ __forceinline__ float bf_lo(unsigned u) { return __uint_as_float(u << 16); }
__device__ __forceinline__ float bf_hi(unsigned u) { return __uint_as_float(u & 0xffff0000u); }

__device__ __forceinline__ v4f mfma16(v4s a, v4s b, v4f c) {
  return __builtin_amdgcn_mfma_f32_16x16x16bf16_1k(a, b, c, 0, 0, 0);
}

// E LDS index (u2 = 8B units) for (t_local in [0,64), x, wblk=w>>2);
// XOR-swizzle keeps write/read bank aliasing near the structural minimum.
__device__ __forceinline__ int eidx(int tl, int x, int wblk) {
  return tl * 64 + x * 4 + (wblk ^ (x >> 2));
}

__global__ __launch_bounds__(64, 1) void fhmm_fwd(
    const float* __restrict__ seq,     // [B, T, D]
    const int*   __restrict__ lengths, // [B]
    const float* __restrict__ pw,      // [16,16]
    const float* __restrict__ px,      // [16,16]
    const float* __restrict__ py,      // [16,16,64]
    float*       __restrict__ out)     // [B]
{
  const int b = blockIdx.x;
  const int l = threadIdx.x;
  const int g = l >> 4;
  const int x = l & 15;

  __shared__ u2    Elds[64 * 64];  // ONE chunk: 64 t × 256 s, bf16 pairs
  __shared__ float Mbuf[512];      // global-t max shifts

  // ---------- init: dif B-frags (bf16 log2-odds), per-state base ----------
  // B-frag 16x16x16: lane (g,x) holds B[k=4g+i][n=x]; dif[s=st*16+x][d=16c+4g+i]
  v4s difB[16][4];
  float bfull[16];
  float bs0 = 0.f, bs1 = 0.f, bs2 = 0.f, bs3 = 0.f;
#pragma unroll
  for (int st = 0; st < 16; ++st) {
    float part = 0.f;
#pragma unroll
    for (int c = 0; c < 4; ++c) {
      f4 p = *(const f4*)(py + (st * 16 + x) * 64 + c * 16 + g * 4);
      float q0 = __log2f(1.f - p.x), q1 = __log2f(1.f - p.y),
            q2 = __log2f(1.f - p.z), q3 = __log2f(1.f - p.w);
      part += (q0 + q1) + (q2 + q3);
      difB[st][c] = mk4(pk_bf16(__log2f(p.x) - q0, __log2f(p.y) - q1),
                        pk_bf16(__log2f(p.z) - q2, __log2f(p.w) - q3));
    }
    part += __shfl_xor(part, 16, 64);  // sum the 4 g-groups (d-slices)
    part += __shfl_xor(part, 32, 64);
    bfull[st] = part;                  // base[st*16 + x] at every lane
    if ((st >> 2) == g) {              // scan needs base for w=4g+i at this x
      if ((st & 3) == 0) bs0 = part;
      if ((st & 3) == 1) bs1 = part;
      if ((st & 3) == 2) bs2 = part;
      if ((st & 3) == 3) bs3 = part;
    }
  }

  // transition B-frags: B[k=4g+i][n=x] = p?[4g+i][x]
  v4s pwB, pxB;
  {
    const int r0 = (4 * g) * 16 + x;
    pwB = mk4(pk_bf16(pw[r0], pw[r0 + 16]), pk_bf16(pw[r0 + 32], pw[r0 + 48]));
    pxB = mk4(pk_bf16(px[r0], px[r0 + 16]), pk_bf16(px[r0 + 32], px[r0 + 48]));
  }
  // priors: alpha0[w][x] needs pw[0][w] (w=4g+i, regs) and px[0][x] (lane)
  const float p0w0 = pw[4 * g + 0], p0w1 = pw[4 * g + 1],
              p0w2 = pw[4 * g + 2], p0w3 = pw[4 * g + 3];
  const float px0 = px[x];

  const int len = lengths[b];
  const int nch = (len + 63) >> 6;
  const float* yb = seq + (size_t)b * (Tt * Dd);

  float acc = 0.f;                   // log2 of renorm factors
  v4f al = {0.f, 0.f, 0.f, 0.f};     // alpha, D-layout: (w=4g+id regs, x lanes)
  const v4f z4 = {0.f, 0.f, 0.f, 0.f};

#pragma unroll 1
  for (int ch = 0; ch < nch; ++ch) {
    const int tb = ch * 64;

    // ======== chunk GEMM: E[t][s] = sum_d y[t][d] dif[s][d], t in [tb,tb+64)
#pragma unroll 1
    for (int mt = 0; mt < 4; ++mt) {
      const int t0 = tb + mt * 16;
      const int tl0 = mt * 16;         // LDS-local t base
      // A-frag: A[m=x][k=4g+i] = y[t0+x][16c+4g+i]; y in {0,1} -> bf16 exact
      f4 yv0 = *(const f4*)(yb + (size_t)(t0 + x) * 64 + 0 + g * 4);
      f4 yv1 = *(const f4*)(yb + (size_t)(t0 + x) * 64 + 16 + g * 4);
      f4 yv2 = *(const f4*)(yb + (size_t)(t0 + x) * 64 + 32 + g * 4);
      f4 yv3 = *(const f4*)(yb + (size_t)(t0 + x) * 64 + 48 + g * 4);
      v4s ya[4];
      ya[0] = mk4(pk_bf16(yv0.x, yv0.y), pk_bf16(yv0.z, yv0.w));
      ya[1] = mk4(pk_bf16(yv1.x, yv1.y), pk_bf16(yv1.z, yv1.w));
      ya[2] = mk4(pk_bf16(yv2.x, yv2.y), pk_bf16(yv2.z, yv2.w));
      ya[3] = mk4(pk_bf16(yv3.x, yv3.y), pk_bf16(yv3.z, yv3.w));
      float mx0 = -1e30f, mx1 = -1e30f, mx2 = -1e30f, mx3 = -1e30f;
#pragma unroll
      for (int q = 0; q < 4; ++q) {   // w-tiles 4q..4q+3
        v4f a0 = z4, a1 = z4, a2 = z4, a3 = z4;
#pragma unroll
        for (int c = 0; c < 4; ++c) {
          a0 = mfma16(ya[c], difB[4 * q + 0][c], a0);
          a1 = mfma16(ya[c], difB[4 * q + 1][c], a1);
          a2 = mfma16(ya[c], difB[4 * q + 2][c], a2);
          a3 = mfma16(ya[c], difB[4 * q + 3][c], a3);
        }
        const float b0 = bfull[4 * q + 0], b1 = bfull[4 * q + 1],
                    b2 = bfull[4 * q + 2], b3 = bfull[4 * q + 3];
        // D layout: lane (g,x) reg id holds t = t0+4g+id, col = x
#pragma unroll
        for (int id = 0; id < 4; ++id) {
          const float e0 = a0[id], e1 = a1[id], e2 = a2[id], e3 = a3[id];
          u2 wv;
          wv.x = pk_bf16(e0, e1);
          wv.y = pk_bf16(e2, e3);
          Elds[eidx(tl0 + 4 * g + id, x, q)] = wv;
          const float mq = fmaxf(fmaxf(e0 + b0, e1 + b1), fmaxf(e2 + b2, e3 + b3));
          if (id == 0) mx0 = fmaxf(mx0, mq);
          if (id == 1) mx1 = fmaxf(mx1, mq);
          if (id == 2) mx2 = fmaxf(mx2, mq);
          if (id == 3) mx3 = fmaxf(mx3, mq);
        }
      }
      // M'[t] = max_s (E + base): reduce over the 16 x-lanes
#pragma unroll
      for (int o = 1; o <= 8; o <<= 1) {
        mx0 = fmaxf(mx0, __shfl_xor(mx0, o, 64));
        mx1 = fmaxf(mx1, __shfl_xor(mx1, o, 64));
        mx2 = fmaxf(mx2, __shfl_xor(mx2, o, 64));
        mx3 = fmaxf(mx3, __shfl_xor(mx3, o, 64));
      }
      if (x == 0) Mbuf[t0 + 4 * g + 0] = mx0;
      if (x == 1) Mbuf[t0 + 4 * g + 1] = mx1;
      if (x == 2) Mbuf[t0 + 4 * g + 2] = mx2;
      if (x == 3) Mbuf[t0 + 4 * g + 3] = mx3;
    }

    __syncthreads();   // GEMM writes -> scan reads

    // ======== scan phase: steps t in [tb, min(len, tb+64)) ========
    const int te = (len < tb + 64) ? len : (tb + 64);
    u2 Ec = Elds[eidx(0, x, g)];
    float Mc = Mbuf[tb];
#pragma unroll 1
    for (int t = tb; t < te; ++t) {
      u2 En = Ec; float Mn = Mc;
      if (t + 1 < te) {                      // prefetch next step's E, M
        En = Elds[eidx((t + 1) & 63, x, g)];
        Mn = Mbuf[t + 1];
      }
      const float e0 = exp2f(fminf(bf_lo(Ec.x) + bs0 - Mc, 4.f));
      const float e1 = exp2f(fminf(bf_hi(Ec.x) + bs1 - Mc, 4.f));
      const float e2 = exp2f(fminf(bf_lo(Ec.y) + bs2 - Mc, 4.f));
      const float e3 = exp2f(fminf(bf_hi(Ec.y) + bs3 - Mc, 4.f));
      if (t == 0) {
        v4f a0v = {p0w0 * px0 * e0, p0w1 * px0 * e1,
                   p0w2 * px0 * e2, p0w3 * px0 * e3};
        al = a0v;
      } else {
        // alpha (D-layout) fed as A is read transposed: A[x][w] = alpha[w][x]
        v4s a16 = mk4(pk_bf16(al[0], al[1]), pk_bf16(al[2], al[3]));
        v4f d1 = mfma16(a16, pwB, z4);   // aw: (xstate regs, w' lanes)
        v4s d16 = mk4(pk_bf16(d1[0], d1[1]), pk_bf16(d1[2], d1[3]));
        v4f d2 = mfma16(d16, pxB, z4);   // an[w'][x'], back in al layout
        v4f anv = {d2[0] * e0, d2[1] * e1, d2[2] * e2, d2[3] * e3};
        al = anv;
      }
      if ((t & 7) == 7) {  // renorm; S >= 2^-74 between renorms (bounded)
        float S = (al[0] + al[1]) + (al[2] + al[3]);
#pragma unroll
        for (int o = 1; o <= 32; o <<= 1) S += __shfl_xor(S, o, 64);
        S = fmaxf(S, 1e-35f);
        const float r = __builtin_amdgcn_rcpf(S);
        al *= r;
        acc += __log2f(S);
      }
      Ec = En; Mc = Mn;
    }

    __syncthreads();   // scan reads done -> next chunk GEMM may overwrite
  }

  // ---------- finalize ----------
  float S = (al[0] + al[1]) + (al[2] + al[3]);
#pragma unroll
  for (int o = 1; o <= 32; o <<= 1) S += __shfl_xor(S, o, 64);
  S = fmaxf(S, 1e-35f);
  acc += __log2f(S);

  float msum = 0.f;
  for (int t = l; t < len; t += 64) msum += Mbuf[t];
#pragma unroll
  for (int o = 1; o <= 32; o <<= 1) msum += __shfl_xor(msum, o, 64);

  if (l == 0) out[b] = LN2 * (acc + msum);
}

} // namespace

extern "C" void kernel_launch(void* const* d_in, const int* in_sizes, int n_in,
                              void* d_out, int out_size, void* d_ws, size_t ws_size,
                              hipStream_t stream) {
  const float* seq     = (const float*)d_in[0];
  const int*   lengths = (const int*)d_in[1];
  const float* pw      = (const float*)d_in[2];
  const float* px      = (const float*)d_in[3];
  const float* py      = (const float*)d_in[4];
  float*       out     = (float*)d_out;

  hipLaunchKernelGGL(fhmm_fwd, dim3(1024), dim3(64), 0, stream,
                     seq, lengths, pw, px, py, out);
}

// Round 8
// 142.667 us; speedup vs baseline: 5.1365x; 1.6215x over previous
//
#include <hip/hip_runtime.h>

namespace {

typedef short    v4s __attribute__((ext_vector_type(4)));
typedef float    v4f __attribute__((ext_vector_type(4)));
typedef float    f4  __attribute__((ext_vector_type(4)));
typedef unsigned u2  __attribute__((ext_vector_type(2)));

constexpr int Tt = 512;
constexpr int Dd = 64;
constexpr float LN2 = 0.69314718055994530942f;

// RNE bf16 pack (bit-twiddle, off-critical-path use only)
__device__ __forceinline__ unsigned pk_bf16(float a, float b) {
  unsigned ua = __float_as_uint(a), ub = __float_as_uint(b);
  ua += 0x7fffu + ((ua >> 16) & 1u);
  ub += 0x7fffu + ((ub >> 16) & 1u);
  return (ua >> 16) | (ub & 0xffff0000u);
}
// 1-instruction truncation pack: {lo16 = hi16(lo), hi16 = hi16(hi)} via v_perm_b32
__device__ __forceinline__ unsigned pktrunc(float lo, float hi) {
  return __builtin_amdgcn_perm(__float_as_uint(hi), __float_as_uint(lo), 0x07060302u);
}
__device__ __forceinline__ v4s mk4(unsigned lo, unsigned hi) {
  union { unsigned u[2]; v4s s; } z;
  z.u[0] = lo; z.u[1] = hi; return z.s;
}
__device__ __forceinline__ float bf_lo(unsigned u) { return __uint_as_float(u << 16); }
__device__ __forceinline__ float bf_hi(unsigned u) { return __uint_as_float(u & 0xffff0000u); }

__device__ __forceinline__ v4f mfma16(v4s a, v4s b, v4f c) {
  return __builtin_amdgcn_mfma_f32_16x16x16bf16_1k(a, b, c, 0, 0, 0);
}
__device__ __forceinline__ float fexp2(float x) {
#if __has_builtin(__builtin_amdgcn_exp2f)
  return __builtin_amdgcn_exp2f(x);
#else
  return exp2f(x);
#endif
}

// E LDS index (u2 = 8B units) for (t_local in [0,64), x, wblk)
__device__ __forceinline__ int eidx(int tl, int x, int wblk) {
  return tl * 64 + x * 4 + (wblk ^ (x >> 2));
}

__global__ __launch_bounds__(64, 1) void fhmm_fwd(
    const float* __restrict__ seq,     // [B, T, D]
    const int*   __restrict__ lengths, // [B]
    const float* __restrict__ pw,      // [16,16]
    const float* __restrict__ px,      // [16,16]
    const float* __restrict__ py,      // [16,16,64]
    float*       __restrict__ out)     // [B]
{
  const int b = blockIdx.x;
  const int l = threadIdx.x;
  const int g = l >> 4;
  const int x = l & 15;

  __shared__ u2    Elds[64 * 64];  // ONE chunk: 64 t × 256 s, bf16(E+base) pairs
  __shared__ float Mbuf[512];      // global-t max shifts

  // ---------- init: dif B-frags (bf16 log2-odds), per-state base ----------
  v4s difB[16][4];
  float bfull[16];
#pragma unroll
  for (int st = 0; st < 16; ++st) {
    float part = 0.f;
#pragma unroll
    for (int c = 0; c < 4; ++c) {
      f4 p = *(const f4*)(py + (st * 16 + x) * 64 + c * 16 + g * 4);
      float q0 = __log2f(1.f - p.x), q1 = __log2f(1.f - p.y),
            q2 = __log2f(1.f - p.z), q3 = __log2f(1.f - p.w);
      part += (q0 + q1) + (q2 + q3);
      difB[st][c] = mk4(pk_bf16(__log2f(p.x) - q0, __log2f(p.y) - q1),
                        pk_bf16(__log2f(p.z) - q2, __log2f(p.w) - q3));
    }
    part += __shfl_xor(part, 16, 64);
    part += __shfl_xor(part, 32, 64);
    bfull[st] = part;   // base[st*16 + x] at every lane of its x
  }

  v4s pwB, pxB;
  {
    const int r0 = (4 * g) * 16 + x;
    pwB = mk4(pk_bf16(pw[r0], pw[r0 + 16]), pk_bf16(pw[r0 + 32], pw[r0 + 48]));
    pxB = mk4(pk_bf16(px[r0], px[r0 + 16]), pk_bf16(px[r0 + 32], px[r0 + 48]));
  }
  const float p0w0 = pw[4 * g + 0], p0w1 = pw[4 * g + 1],
              p0w2 = pw[4 * g + 2], p0w3 = pw[4 * g + 3];
  const float px0 = px[x];

  const int len = lengths[b];
  const int nch = (len + 63) >> 6;
  const float* yb = seq + (size_t)b * (Tt * Dd);

  float acc = 0.f;
  v4f al = {0.f, 0.f, 0.f, 0.f};
  const v4f z4 = {0.f, 0.f, 0.f, 0.f};

#pragma unroll 1
  for (int ch = 0; ch < nch; ++ch) {
    const int tb = ch * 64;

    // ======== chunk GEMM: E'[t][s] = base[s] + sum_d y[t][d] dif[s][d] ========
#pragma unroll 2
    for (int mt = 0; mt < 4; ++mt) {
      const int t0 = tb + mt * 16;
      const int tl0 = mt * 16;
      f4 yv0 = *(const f4*)(yb + (size_t)(t0 + x) * 64 + 0 + g * 4);
      f4 yv1 = *(const f4*)(yb + (size_t)(t0 + x) * 64 + 16 + g * 4);
      f4 yv2 = *(const f4*)(yb + (size_t)(t0 + x) * 64 + 32 + g * 4);
      f4 yv3 = *(const f4*)(yb + (size_t)(t0 + x) * 64 + 48 + g * 4);
      v4s ya[4];
      ya[0] = mk4(pk_bf16(yv0.x, yv0.y), pk_bf16(yv0.z, yv0.w));
      ya[1] = mk4(pk_bf16(yv1.x, yv1.y), pk_bf16(yv1.z, yv1.w));
      ya[2] = mk4(pk_bf16(yv2.x, yv2.y), pk_bf16(yv2.z, yv2.w));
      ya[3] = mk4(pk_bf16(yv3.x, yv3.y), pk_bf16(yv3.z, yv3.w));
      float mx0 = -1e30f, mx1 = -1e30f, mx2 = -1e30f, mx3 = -1e30f;
#pragma unroll
      for (int q = 0; q < 4; ++q) {
        v4f a0 = z4, a1 = z4, a2 = z4, a3 = z4;
#pragma unroll
        for (int c = 0; c < 4; ++c) {
          a0 = mfma16(ya[c], difB[4 * q + 0][c], a0);
          a1 = mfma16(ya[c], difB[4 * q + 1][c], a1);
          a2 = mfma16(ya[c], difB[4 * q + 2][c], a2);
          a3 = mfma16(ya[c], difB[4 * q + 3][c], a3);
        }
        const float b0 = bfull[4 * q + 0], b1 = bfull[4 * q + 1],
                    b2 = bfull[4 * q + 2], b3 = bfull[4 * q + 3];
#pragma unroll
        for (int id = 0; id < 4; ++id) {
          const float e0 = a0[id] + b0, e1 = a1[id] + b1,
                      e2 = a2[id] + b2, e3 = a3[id] + b3;
          u2 wv;
          wv.x = pk_bf16(e0, e1);
          wv.y = pk_bf16(e2, e3);
          Elds[eidx(tl0 + 4 * g + id, x, q)] = wv;
          const float mq = fmaxf(fmaxf(e0, e1), fmaxf(e2, e3));
          if (id == 0) mx0 = fmaxf(mx0, mq);
          if (id == 1) mx1 = fmaxf(mx1, mq);
          if (id == 2) mx2 = fmaxf(mx2, mq);
          if (id == 3) mx3 = fmaxf(mx3, mq);
        }
      }
#pragma unroll
      for (int o = 1; o <= 8; o <<= 1) {
        mx0 = fmaxf(mx0, __shfl_xor(mx0, o, 64));
        mx1 = fmaxf(mx1, __shfl_xor(mx1, o, 64));
        mx2 = fmaxf(mx2, __shfl_xor(mx2, o, 64));
        mx3 = fmaxf(mx3, __shfl_xor(mx3, o, 64));
      }
      if (x == 0) Mbuf[t0 + 4 * g + 0] = mx0;
      if (x == 1) Mbuf[t0 + 4 * g + 1] = mx1;
      if (x == 2) Mbuf[t0 + 4 * g + 2] = mx2;
      if (x == 3) Mbuf[t0 + 4 * g + 3] = mx3;
    }

    __syncthreads();   // GEMM writes -> scan reads

    // ======== scan phase: steps t in [tb, te) ========
    const int te = (len < tb + 64) ? len : (tb + 64);
    int t = tb;
    u2 Ec = Elds[eidx(0, x, g)];
    float Mc = Mbuf[tb];

// one scan step; PF = prefetch statement(s) filling En_/Mn_
#define SCAN_STEP(PF)                                                       \
    {                                                                       \
      u2 En_ = Ec; float Mn_ = Mc;                                          \
      PF                                                                    \
      const float e0 = fexp2(bf_lo(Ec.x) - Mc);                             \
      const float e1 = fexp2(bf_hi(Ec.x) - Mc);                             \
      const float e2 = fexp2(bf_lo(Ec.y) - Mc);                             \
      const float e3 = fexp2(bf_hi(Ec.y) - Mc);                             \
      v4s a16 = mk4(pktrunc(al[0], al[1]), pktrunc(al[2], al[3]));          \
      v4f d1 = mfma16(a16, pwB, z4);                                        \
      v4s d16 = mk4(pktrunc(d1[0], d1[1]), pktrunc(d1[2], d1[3]));          \
      v4f d2 = mfma16(d16, pxB, z4);                                        \
      al[0] = d2[0] * e0; al[1] = d2[1] * e1;                               \
      al[2] = d2[2] * e2; al[3] = d2[3] * e3;                               \
      Ec = En_; Mc = Mn_;                                                   \
    }

#define RENORM                                                              \
    {                                                                       \
      float S = (al[0] + al[1]) + (al[2] + al[3]);                          \
      _Pragma("unroll")                                                     \
      for (int o = 1; o <= 32; o <<= 1) S += __shfl_xor(S, o, 64);          \
      S = fmaxf(S, 1e-35f);                                                 \
      const float r = __builtin_amdgcn_rcpf(S);                             \
      al[0] *= r; al[1] *= r; al[2] *= r; al[3] *= r;                       \
      acc += __log2f(S);                                                    \
    }

    if (ch == 0) {   // peel t = 0: alpha0 = prior * e
      const float e0 = fexp2(bf_lo(Ec.x) - Mc);
      const float e1 = fexp2(bf_hi(Ec.x) - Mc);
      const float e2 = fexp2(bf_lo(Ec.y) - Mc);
      const float e3 = fexp2(bf_hi(Ec.y) - Mc);
      al[0] = p0w0 * px0 * e0; al[1] = p0w1 * px0 * e1;
      al[2] = p0w2 * px0 * e2; al[3] = p0w3 * px0 * e3;
      t = 1;
      if (t < te) { Ec = Elds[eidx(1, x, g)]; Mc = Mbuf[1]; }
    }

    // guarded entry until 8-aligned (or te)
    while (t < te && (t & 7)) {
      SCAN_STEP(
        if (t + 1 < te) { En_ = Elds[eidx((t + 1) & 63, x, g)]; Mn_ = Mbuf[t + 1]; })
      if ((t & 7) == 7) RENORM
      ++t;
    }
    // fast path: full 8-step groups, unconditional prefetch, renorm per group
    while (t + 8 <= te) {
#pragma unroll
      for (int k = 0; k < 8; ++k) {
        const int tn = t + k + 1;
        SCAN_STEP(
          En_ = Elds[eidx(tn & 63, x, g)]; Mn_ = Mbuf[tn < 511 ? tn : 511];)
      }
      RENORM
      t += 8;
    }
    // guarded tail
    while (t < te) {
      SCAN_STEP(
        if (t + 1 < te) { En_ = Elds[eidx((t + 1) & 63, x, g)]; Mn_ = Mbuf[t + 1]; })
      if ((t & 7) == 7) RENORM
      ++t;
    }
#undef SCAN_STEP
#undef RENORM

    __syncthreads();   // scan reads done -> next chunk GEMM may overwrite
  }

  // ---------- finalize ----------
  float S = (al[0] + al[1]) + (al[2] + al[3]);
#pragma unroll
  for (int o = 1; o <= 32; o <<= 1) S += __shfl_xor(S, o, 64);
  S = fmaxf(S, 1e-35f);
  acc += __log2f(S);

  float msum = 0.f;
  for (int t2 = l; t2 < len; t2 += 64) msum += Mbuf[t2];
#pragma unroll
  for (int o = 1; o <= 32; o <<= 1) msum += __shfl_xor(msum, o, 64);

  if (l == 0) out[b] = LN2 * (acc + msum);
}

} // namespace

extern "C" void kernel_launch(void* const* d_in, const int* in_sizes, int n_in,
                              void* d_out, int out_size, void* d_ws, size_t ws_size,
                              hipStream_t stream) {
  const float* seq     = (const float*)d_in[0];
  const int*   lengths = (const int*)d_in[1];
  const float* pw      = (const float*)d_in[2];
  const float* px      = (const float*)d_in[3];
  const float* py      = (const float*)d_in[4];
  float*       out     = (float*)d_out;

  hipLaunchKernelGGL(fhmm_fwd, dim3(1024), dim3(64), 0, stream,
                     seq, lengths, pw, px, py, out);
}